// Round 9
// baseline (130.542 us; speedup 1.0000x reference)
//
#include <hip/hip_runtime.h>
#include <hip/hip_bf16.h>

#define C_ 384
#define B_ 16
#define H_ 56
#define W_ 56
#define TPB_ 256

// Fold all 7 branches (conv + BN) into one 13x13 kernel per channel + bias.
// weff layout: [C][13][16] (rows padded to 16 floats for aligned scalar loads)
__global__ void build_weights_kernel(
    const float* __restrict__ lk, const float* __restrict__ obn,
    const float* __restrict__ w5, const float* __restrict__ w7a,
    const float* __restrict__ w7b, const float* __restrict__ w3a,
    const float* __restrict__ w3b, const float* __restrict__ w3c,
    const float* __restrict__ brbn,
    float* __restrict__ weff, float* __restrict__ bias)
{
    int c = blockIdx.x;
    int t = threadIdx.x;

    float sc[7], sh[7];
    {
        float g = obn[c], b = obn[C_ + c], m = obn[2 * C_ + c], v = obn[3 * C_ + c];
        float s = g * rsqrtf(v + 1e-5f);
        sc[0] = s; sh[0] = b - m * s;
    }
#pragma unroll
    for (int i = 0; i < 6; ++i) {
        float g = brbn[(i * 4 + 0) * C_ + c], b = brbn[(i * 4 + 1) * C_ + c];
        float m = brbn[(i * 4 + 2) * C_ + c], v = brbn[(i * 4 + 3) * C_ + c];
        float s = g * rsqrtf(v + 1e-5f);
        sc[i + 1] = s; sh[i + 1] = b - m * s;
    }

    if (t < 13 * 16) {
        int py = t >> 4, px = t & 15;
        float a = 0.f;
        if (px < 13) {
            int dy = py - 6, dx = px - 6;
            a = sc[0] * lk[c * 169 + py * 13 + px];   // 13x13, dil 1
#define ADDBR(Wp, K, R, SI)                                               \
            {                                                             \
                const int half = ((K) - 1) / 2;                           \
                if (dy % (R) == 0 && dx % (R) == 0) {                     \
                    int iy = dy / (R), ix = dx / (R);                     \
                    if (iy >= -half && iy <= half && ix >= -half && ix <= half) \
                        a += sc[SI] * Wp[c * (K) * (K) + (iy + half) * (K) + (ix + half)]; \
                }                                                         \
            }
            ADDBR(w5,  5, 1, 1)
            ADDBR(w7a, 7, 1, 2)
            ADDBR(w7b, 7, 2, 3)
            ADDBR(w3a, 3, 3, 4)
            ADDBR(w3b, 3, 4, 5)
            ADDBR(w3c, 3, 5, 6)
#undef ADDBR
        }
        weff[c * 208 + t] = a;
    }
    if (t == 0) {
        float s = 0.f;
#pragma unroll
        for (int i = 0; i < 7; ++i) s += sh[i];
        bias[c] = s;
    }
}

// LDS-free direct conv: one thread = 4-wide x 7-tall output tile, rows
// streamed straight from global (L1/L2 provide the reuse; active window per
// block ~17KB). Padding: addresses CLAMPED into the plane (always legal),
// values zeroed by select. Col chunks have no partial validity (parity).
// Data on vmcnt; block-uniform weights on lgkm s_load - decoupled counters.
__global__ __launch_bounds__(TPB_, 4) void dwconv13_direct(
    const float* __restrict__ x, const float* __restrict__ weff,
    const float* __restrict__ bias, float* __restrict__ out)
{
    const int c   = blockIdx.y;
    const int gid = blockIdx.x * TPB_ + threadIdx.x;   // 0..1791
    const int b   = gid / 112;
    const int r   = gid - b * 112;
    const int xg  = r % 14;
    const int yg  = r / 14;
    const int x0  = xg * 4, y0 = yg * 7;

    const float* xp = x + ((size_t)b * C_ + c) * (H_ * W_);

    // Per-chunk col validity + clamped byte offset (chunk j = cols x0-6+2j,+1;
    // clo is always even and W is even -> chunks are all-valid or all-invalid).
    bool cv[8];
    int  cb[8];
#pragma unroll
    for (int j = 0; j < 8; ++j) {
        int clo = x0 - 6 + 2 * j;
        cv[j] = (unsigned)clo < (unsigned)W_;
        cb[j] = (cv[j] ? clo : 0) * 4;
    }

    const float* wc = weff + c * 208;   // block-uniform -> s_load path
    float bv = bias[c];

    float acc[7][4];
#pragma unroll
    for (int i = 0; i < 7; ++i)
#pragma unroll
        for (int j = 0; j < 4; ++j) acc[i][j] = bv;

    float2 A2[8], B2[8];

#define LOADROWG(buf, rr) {                                                \
        int  iy_ = y0 - 6 + (rr);                                          \
        bool rv_ = (unsigned)iy_ < (unsigned)H_;                           \
        const char* rp_ = (const char*)(xp + (rv_ ? iy_ : 0) * W_);        \
        _Pragma("unroll")                                                  \
        for (int j = 0; j < 8; ++j) {                                      \
            float2 v_ = *(const float2*)(rp_ + cb[j]);                     \
            bool ok_ = rv_ && cv[j];                                       \
            (buf)[j].x = ok_ ? v_.x : 0.f;                                 \
            (buf)[j].y = ok_ ? v_.y : 0.f;                                 \
        }                                                                  \
    }

#define DOROW(buf, rr) {                                                   \
        _Pragma("unroll")                                                  \
        for (int tt = 0; tt < 7; ++tt) {                                   \
            int ky = (rr) - tt;                                            \
            if (ky >= 0 && ky <= 12) {   /* compile-time after unroll */   \
                const float* wrow = wc + ky * 16;                          \
                _Pragma("unroll")                                          \
                for (int kx = 0; kx < 13; ++kx) {                          \
                    float w = wrow[kx];                                    \
                    _Pragma("unroll")                                      \
                    for (int j = 0; j < 4; ++j) {                          \
                        int k = kx + j;                                    \
                        float v = (k & 1) ? (buf)[k >> 1].y                \
                                          : (buf)[k >> 1].x;               \
                        acc[tt][j] = fmaf(w, v, acc[tt][j]);               \
                    }                                                      \
                }                                                          \
            }                                                              \
        }                                                                  \
    }

    // 2-deep double-buffered sliding window over the 19 input rows.
    LOADROWG(A2, 0)
#pragma unroll
    for (int rb = 0; rb < 10; ++rb) {
        const int ra = 2 * rb;
        if (ra + 1 < 19) LOADROWG(B2, ra + 1)
        DOROW(A2, ra)
        if (ra + 2 < 19) LOADROWG(A2, ra + 2)
        if (ra + 1 < 19) DOROW(B2, ra + 1)
    }
#undef DOROW
#undef LOADROWG

    float* op = out + ((size_t)b * C_ + c) * (H_ * W_);
#pragma unroll
    for (int tt = 0; tt < 7; ++tt) {
        float4 v = make_float4(acc[tt][0], acc[tt][1], acc[tt][2], acc[tt][3]);
        *(float4*)(op + (y0 + tt) * W_ + x0) = v;
    }
}

extern "C" void kernel_launch(void* const* d_in, const int* in_sizes, int n_in,
                              void* d_out, int out_size, void* d_ws, size_t ws_size,
                              hipStream_t stream) {
    const float* x    = (const float*)d_in[0];
    const float* lk   = (const float*)d_in[1];
    const float* obn  = (const float*)d_in[2];
    const float* w5   = (const float*)d_in[3];
    const float* w7a  = (const float*)d_in[4];
    const float* w7b  = (const float*)d_in[5];
    const float* w3a  = (const float*)d_in[6];
    const float* w3b  = (const float*)d_in[7];
    const float* w3c  = (const float*)d_in[8];
    const float* brbn = (const float*)d_in[9];
    float* out  = (float*)d_out;

    float* weff = (float*)d_ws;            // 384*208 floats = 319488 B
    float* bias = weff + C_ * 208;         // 384 floats

    hipLaunchKernelGGL(build_weights_kernel, dim3(C_), dim3(256), 0, stream,
                       lk, obn, w5, w7a, w7b, w3a, w3b, w3c, brbn, weff, bias);

    hipLaunchKernelGGL(dwconv13_direct, dim3(7, C_), dim3(TPB_), 0, stream,
                       x, weff, bias, out);
}

// Round 10
// 93.644 us; speedup vs baseline: 1.3940x; 1.3940x over previous
//
#include <hip/hip_runtime.h>
#include <hip/hip_bf16.h>

#define C_ 384
#define B_ 16
#define H_ 56
#define W_ 56
#define PAD_ 6
#define NPL_ 4               // planes per block
#define TPB_ 448             // 7 waves; 112 threads per plane
#define PLANE32_ 2312        // 68 rows * 34 u32 (f16 pairs) per plane
#define WROW_ 8              // u32 weight-pairs per ky row (7 used + pad)

typedef _Float16 half2v __attribute__((ext_vector_type(2)));

// ---- folded weight value for (c, py, px), px<13 ----
__device__ __forceinline__ float foldw(int c, int py, int px,
    const float* lk, const float* w5, const float* w7a, const float* w7b,
    const float* w3a, const float* w3b, const float* w3c, const float* sc)
{
    int dy = py - 6, dx = px - 6;
    float a = sc[0] * lk[c * 169 + py * 13 + px];
#define ADDBR(Wp, K, R, SI)                                               \
    {                                                                     \
        const int half = ((K) - 1) / 2;                                   \
        if (dy % (R) == 0 && dx % (R) == 0) {                             \
            int iy = dy / (R), ix = dx / (R);                             \
            if (iy >= -half && iy <= half && ix >= -half && ix <= half)   \
                a += sc[SI] * Wp[c * (K) * (K) + (iy + half) * (K) + (ix + half)]; \
        }                                                                 \
    }
    ADDBR(w5,  5, 1, 1)
    ADDBR(w7a, 7, 1, 2)
    ADDBR(w7b, 7, 2, 3)
    ADDBR(w3a, 3, 3, 4)
    ADDBR(w3b, 3, 4, 5)
    ADDBR(w3c, 3, 5, 6)
#undef ADDBR
    return a;
}

// Fold 7 branches (conv+BN) into one 13x13 kernel per channel, stored as
// f16 PAIRS for v_dot2: wpk[c][ky][p] = half2(w[2p], w[2p+1]), w[13..15]=0.
__global__ void build_weights_kernel(
    const float* __restrict__ lk, const float* __restrict__ obn,
    const float* __restrict__ w5, const float* __restrict__ w7a,
    const float* __restrict__ w7b, const float* __restrict__ w3a,
    const float* __restrict__ w3b, const float* __restrict__ w3c,
    const float* __restrict__ brbn,
    unsigned* __restrict__ wpk, float* __restrict__ bias)
{
    int c = blockIdx.x;
    int t = threadIdx.x;

    float sc[7], sh[7];
    {
        float g = obn[c], b = obn[C_ + c], m = obn[2 * C_ + c], v = obn[3 * C_ + c];
        float s = g * rsqrtf(v + 1e-5f);
        sc[0] = s; sh[0] = b - m * s;
    }
#pragma unroll
    for (int i = 0; i < 6; ++i) {
        float g = brbn[(i * 4 + 0) * C_ + c], b = brbn[(i * 4 + 1) * C_ + c];
        float m = brbn[(i * 4 + 2) * C_ + c], v = brbn[(i * 4 + 3) * C_ + c];
        float s = g * rsqrtf(v + 1e-5f);
        sc[i + 1] = s; sh[i + 1] = b - m * s;
    }

    if (t < 13 * WROW_) {
        int ky = t / WROW_, pp = t % WROW_;
        int kx0 = 2 * pp, kx1 = 2 * pp + 1;
        float w0 = (kx0 < 13) ? foldw(c, ky, kx0, lk, w5, w7a, w7b, w3a, w3b, w3c, sc) : 0.f;
        float w1 = (kx1 < 13) ? foldw(c, ky, kx1, lk, w5, w7a, w7b, w3a, w3b, w3c, sc) : 0.f;
        _Float16 h0 = (_Float16)w0, h1 = (_Float16)w1;
        unsigned u = ((unsigned)__builtin_bit_cast(unsigned short, h1) << 16)
                   |  (unsigned)__builtin_bit_cast(unsigned short, h0);
        wpk[c * 13 * WROW_ + t] = u;
    }
    if (t == 0) {
        float s = 0.f;
#pragma unroll
        for (int i = 0; i < 7; ++i) s += sh[i];
        bias[c] = s;
    }
}

// One block: 4 planes of channel c staged in LDS as f16 pairs (37KB ->
// 4 blocks/CU, 2x the old occupancy). Inner loop: v_dot2_f32_f16, 7 dot2
// per 13-tap row (2 MAC/instr, f32 accumulate) - halves the VALU floor.
// Odd-phase input pairs built per row with 8 v_alignbit_b32.
__global__ __launch_bounds__(TPB_) void dwconv13_kernel(
    const float* __restrict__ x, const unsigned* __restrict__ wpk,
    const float* __restrict__ bias, float* __restrict__ out)
{
    __shared__ unsigned sxu[NPL_ * PLANE32_];   // 36992 B

    int bid = blockIdx.x;
    int c  = bid % C_;
    int bg = bid / C_;
    int t  = threadIdx.x;

    // ---- Stage: 4*56 rows * 28 f16-pairs = 6272 u32 -> 14 per thread. ----
    unsigned vvp[14]; int ddp[14];
#pragma unroll
    for (int k = 0; k < 14; ++k) {
        int slot = t + k * TPB_;
        int p    = slot / 1568;            // 1568 = 56*28
        int rem  = slot - p * 1568;
        int iy   = rem / 28;
        int pr   = rem - iy * 28;
        const float* xp = x + ((size_t)(bg * NPL_ + p) * C_ + c) * (H_ * W_);
        float2 v = *(const float2*)(xp + iy * W_ + pr * 2);
        _Float16 h0 = (_Float16)v.x, h1 = (_Float16)v.y;   // RNE converts
        vvp[k] = ((unsigned)__builtin_bit_cast(unsigned short, h1) << 16)
               |  (unsigned)__builtin_bit_cast(unsigned short, h0);
        ddp[k] = p * PLANE32_ + (iy + PAD_) * 34 + 3 + pr; // f16 col 6+2pr
    }

    // ---- Zero whole LDS (halo = padding): 9248 u32 = 2312 uint4. ----
    {
        uint4 z = make_uint4(0u, 0u, 0u, 0u);
        uint4* s4 = (uint4*)sxu;
#pragma unroll
        for (int k = 0; k < 6; ++k) {
            int slot = t + k * TPB_;
            if (k < 5 || slot < 2312) s4[slot] = z;
        }
    }
    __syncthreads();

#pragma unroll
    for (int k = 0; k < 14; ++k) sxu[ddp[k]] = vvp[k];
    __syncthreads();

    const unsigned* wcu = wpk + c * 13 * WROW_;   // block-uniform -> s_load
    float bv = bias[c];

    int p   = t / 112;
    int r   = t - p * 112;
    int yg  = r & 7;          // yg-major lane map (R6's win)
    int xg  = r >> 3;
    int x0 = xg * 4, y0 = yg * 7;
    const unsigned* sp32 = sxu + p * PLANE32_;

    float acc[7][4];
#pragma unroll
    for (int i = 0; i < 7; ++i)
#pragma unroll
        for (int j = 0; j < 4; ++j) acc[i][j] = bv;

    // Row window = 8 u32 (16 f16), pair-aligned: 4x ds_read_b64.
#define LOADROW(Eb, rr) {                                                  \
        const unsigned* rp_ = sp32 + (y0 + (rr)) * 34 + 2 * xg;            \
        *(uint2*)((Eb) + 0) = *(const uint2*)(rp_ + 0);                    \
        *(uint2*)((Eb) + 2) = *(const uint2*)(rp_ + 2);                    \
        *(uint2*)((Eb) + 4) = *(const uint2*)(rp_ + 4);                    \
        *(uint2*)((Eb) + 6) = *(const uint2*)(rp_ + 6);                    \
    }

    // Per row: odd-phase pairs via alignbit, then 7 dot2 per (tt,j).
#define DOROW(Eb, rr) {                                                    \
        unsigned Ob[8];                                                    \
        _Pragma("unroll")                                                  \
        for (int q = 0; q < 7; ++q)                                        \
            Ob[q] = __builtin_amdgcn_alignbit((Eb)[q + 1], (Eb)[q], 16);   \
        Ob[7] = (Eb)[7] >> 16;                                             \
        _Pragma("unroll")                                                  \
        for (int tt = 0; tt < 7; ++tt) {                                   \
            int ky = (rr) - tt;                                            \
            if (ky >= 0 && ky <= 12) {   /* compile-time after unroll */   \
                const unsigned* wr_ = wcu + ky * WROW_;                    \
                _Pragma("unroll")                                          \
                for (int j = 0; j < 4; ++j) {                              \
                    int q0 = j >> 1;                                       \
                    _Pragma("unroll")                                      \
                    for (int p6 = 0; p6 < 7; ++p6) {                       \
                        unsigned iv = (j & 1) ? Ob[q0 + p6] : (Eb)[q0 + p6]; \
                        acc[tt][j] = __builtin_amdgcn_fdot2(               \
                            __builtin_bit_cast(half2v, iv),                \
                            __builtin_bit_cast(half2v, wr_[p6]),           \
                            acc[tt][j], false);                            \
                    }                                                      \
                }                                                          \
            }                                                              \
        }                                                                  \
    }

    // 2-deep double-buffered sliding window over the 19 padded input rows.
    unsigned E0[8], E1[8];
    LOADROW(E0, 0)
#pragma unroll
    for (int rb = 0; rb < 10; ++rb) {
        const int ra = 2 * rb;
        if (ra + 1 < 19) LOADROW(E1, ra + 1)
        DOROW(E0, ra)
        if (ra + 2 < 19) LOADROW(E0, ra + 2)
        if (ra + 1 < 19) DOROW(E1, ra + 1)
    }
#undef DOROW
#undef LOADROW

    float* op = out + ((size_t)(bg * NPL_ + p) * C_ + c) * (H_ * W_);
#pragma unroll
    for (int tt = 0; tt < 7; ++tt) {
        float4 v = make_float4(acc[tt][0], acc[tt][1], acc[tt][2], acc[tt][3]);
        *(float4*)(op + (y0 + tt) * W_ + x0) = v;
    }
}

extern "C" void kernel_launch(void* const* d_in, const int* in_sizes, int n_in,
                              void* d_out, int out_size, void* d_ws, size_t ws_size,
                              hipStream_t stream) {
    const float* x    = (const float*)d_in[0];
    const float* lk   = (const float*)d_in[1];
    const float* obn  = (const float*)d_in[2];
    const float* w5   = (const float*)d_in[3];
    const float* w7a  = (const float*)d_in[4];
    const float* w7b  = (const float*)d_in[5];
    const float* w3a  = (const float*)d_in[6];
    const float* w3b  = (const float*)d_in[7];
    const float* w3c  = (const float*)d_in[8];
    const float* brbn = (const float*)d_in[9];
    float* out  = (float*)d_out;

    unsigned* wpk = (unsigned*)d_ws;             // 384*104 u32 = 159744 B
    float*    bias = (float*)(wpk + C_ * 13 * WROW_);  // 384 floats

    hipLaunchKernelGGL(build_weights_kernel, dim3(C_), dim3(128), 0, stream,
                       lk, obn, w5, w7a, w7b, w3a, w3b, w3c, brbn, wpk, bias);

    hipLaunchKernelGGL(dwconv13_kernel, dim3((B_ / NPL_) * C_), dim3(TPB_), 0, stream,
                       x, wpk, bias, out);
}